// Round 20
// baseline (114.292 us; speedup 1.0000x reference)
//
#include <hip/hip_runtime.h>

typedef unsigned int uint32;
typedef unsigned short ushrt;
typedef __attribute__((ext_vector_type(4))) float f32x4;
typedef __attribute__((ext_vector_type(16))) float f32x16;
typedef __attribute__((ext_vector_type(2))) float f32x2;
typedef __attribute__((ext_vector_type(8))) _Float16 halfx8;
typedef __attribute__((ext_vector_type(4))) uint32 uint32x4;

#define N_NODES 10000
#define N_EDGES 320000

// scales
#define SC_W1      0.17677669529663687f   // 1/sqrt(32)
#define SC_MLP1    0.35355339059327373f   // 1/sqrt(8)
#define SC_MLP2    0.125f                 // 1/sqrt(64)
#define INV_SQRT3  0.5773502691896258f
#define COS_MIX    0.9238795325112867f    // cos(pi/8)
#define SIN_CONV   0.04783542904563623f   // sin(pi/8) / sqrt(64)

// ws layout
#define WS_FEATP 0        // [N][128] floats, planar: f0 | f1x | f1y | f1z
#define I_CNT    1280000  // [N+1]
#define I_OFF    1290016  // [N+1]  (mutated by mlp branch; gather uses off-cnt)
#define U_REC    1300032  // [E] uint4: {ea.y, ea.z, ea.w bits, src}
#define U_WF     2580032  // 26 frags x 64 lanes x 4 uints (32x32 MFMA layout)
#define U_WBUF   2587200  // [E][32] uints = [E][64] fp8-pairs (128B rows), CSR order

__device__ __forceinline__ uint32 packh2(float a, float b) {
    _Float16 ha = (_Float16)a, hb = (_Float16)b;
    return (uint32)__builtin_bit_cast(unsigned short, ha) |
           ((uint32)__builtin_bit_cast(unsigned short, hb) << 16);
}
__device__ __forceinline__ unsigned short h16(float x) {
    _Float16 h = (_Float16)x;
    return __builtin_bit_cast(unsigned short, h);
}
__device__ __forceinline__ unsigned short pack_fp8_2(float a, float b) {
    return (unsigned short)(__builtin_amdgcn_cvt_pk_fp8_f32(a, b, 0, false) & 0xffff);
}
__device__ __forceinline__ float gelu_fast(float x) {
    float x2 = x * x;
    float z = x * __builtin_fmaf(0.03567740814f, x2, 0.7978845608f);
    float E = __builtin_amdgcn_exp2f(z * -2.885390082f);
    return x * __builtin_amdgcn_rcpf(1.0f + E);
}

// ================= K0: zero_cnt =================
__global__ __launch_bounds__(256) void zero_cnt(int* __restrict__ cnt) {
    int i = blockIdx.x * 256 + threadIdx.x;   // grid 40: 10240 >= 10001
    if (i <= N_NODES) cnt[i] = 0;
}

// ================= K1: csr_count | prep_frags (32x32 fragment layout) ========
#define K1_CNT_BLOCKS  1250
#define K1_PREP_BLOCKS 7
__global__ __launch_bounds__(256) void k1_fused(
        const int* __restrict__ edge_dst, int* __restrict__ cnt,
        const float* __restrict__ Wm1, const float* __restrict__ Wm2,
        const float* __restrict__ Wp00, const float* __restrict__ Wp01,
        const float* __restrict__ Wp10, const float* __restrict__ Wp11,
        uint32* __restrict__ wf) {
    int b = blockIdx.x;
    if (b < K1_CNT_BLOCKS) {
        int e = b * 256 + threadIdx.x;
        atomicAdd(&cnt[edge_dst[e]], 1);
    } else {
        int gid = (b - K1_CNT_BLOCKS) * 256 + threadIdx.x;
        if (gid >= 26 * 64) return;
        int f = gid >> 6, lane = gid & 63;
        int kb = (lane >> 5) * 8;
        int c31 = lane & 31;
        float vals[8];
        if (f < 2) {
            int c = 32 * f + c31;
#pragma unroll
            for (int j = 0; j < 8; ++j) { int k = kb + j; vals[j] = (k < 8) ? Wm1[k * 64 + c] : 0.f; }
        } else if (f < 10) {
            int idx = f - 2, nc = idx >> 2, ks = idx & 3;
            int c = 32 * nc + c31;
#pragma unroll
            for (int j = 0; j < 8; ++j) { int k = 16 * ks + kb + j; vals[j] = Wm2[k * 64 + c]; }
        } else {
            int idx = f - 10, m = idx >> 2, ks = idx & 3;
            const float* W = (m == 0) ? Wp00 : (m == 1) ? Wp01 : (m == 2) ? Wp10 : Wp11;
            float sc = (m == 3) ? 0.125f * INV_SQRT3 : 0.125f;
#pragma unroll
            for (int j = 0; j < 8; ++j) { int k = 16 * ks + kb + j; vals[j] = W[k * 32 + c31] * sc; }
        }
        uint32* o = wf + f * 256 + lane * 4;
#pragma unroll
        for (int w = 0; w < 4; ++w) o[w] = packh2(vals[2 * w], vals[2 * w + 1]);
    }
}

// ================= K2: csr_scan (wave-shuffle, 2 barriers total) =============
__global__ __launch_bounds__(1024) void csr_scan(const int* __restrict__ cnt,
                                                 int* __restrict__ off) {
    __shared__ int wsum[16];
    __shared__ int wbase[16];
    int t = threadIdx.x;
    int lane = t & 63, wv = t >> 6;
    const int CHUNK = 10;                    // 1024*10 = 10240 >= 10000
    int base = t * CHUNK;
    int vals[CHUNK];
    int s = 0;
#pragma unroll
    for (int j = 0; j < CHUNK; ++j) {
        int idx = base + j;
        vals[j] = (idx < N_NODES) ? cnt[idx] : 0;
        s += vals[j];
    }
    // wave-level inclusive scan (no barriers)
    int incl = s;
#pragma unroll
    for (int o = 1; o < 64; o <<= 1) {
        int n = __shfl_up(incl, o);
        if (lane >= o) incl += n;
    }
    if (lane == 63) wsum[wv] = incl;
    __syncthreads();
    if (t < 16) {
        int v = wsum[t];
        int p = v;
#pragma unroll
        for (int o = 1; o < 16; o <<= 1) {
            int n = __shfl_up(p, o);
            if (t >= o) p += n;
        }
        wbase[t] = p - v;                    // exclusive inter-wave base
    }
    __syncthreads();
    int run = wbase[wv] + incl - s;          // exclusive prefix for this thread
#pragma unroll
    for (int j = 0; j < CHUNK; ++j) {
        int idx = base + j;
        if (idx < N_NODES) {
            off[idx] = run;
            run += vals[j];
        }
    }
    if (t == 1023) off[N_NODES] = run;
}

// ================= K3: mlp_scatter (32-edge groups, 32x32 MFMA) + node ======
#define MLP_BLOCKS 1250
#define K3_NODE_BLOCKS 2500
__global__ __launch_bounds__(256, 3) void k3_fused(
        const float* __restrict__ edge_scalar, const float* __restrict__ edge_attr,
        const int* __restrict__ src_in, const int* __restrict__ dst_in,
        int* __restrict__ off,
        const uint32* __restrict__ wf,
        uint32* __restrict__ wbuf, uint4* __restrict__ rec,
        const float* __restrict__ x,
        const float* __restrict__ W1_0e, const float* __restrict__ W1_1o,
        float* __restrict__ featp, float* __restrict__ out) {
    __shared__ uint32x4 wfl[26 * 64];        // 26KB: all weight fragments
    __shared__ unsigned short sh[4][2048];   // 16KB: per-wave 32x64 f16 tile / fp8 ob
    __shared__ float eaxs[4][32];
    __shared__ int   poss[4][32];
    __shared__ float xrow[4][128];           // node branch

    int lane = threadIdx.x & 63;
    int wvq = threadIdx.x >> 6;

    if (blockIdx.x >= MLP_BLOCKS) {
        // ---- node_transform ----
        int node = (blockIdx.x - MLP_BLOCKS) * 4 + wvq;
        float2 v = *(const float2*)(x + (size_t)node * 128 + lane * 2);
        xrow[wvq][lane * 2]     = v.x;
        xrow[wvq][lane * 2 + 1] = v.y;
        __syncthreads();
        const float* sx = xrow[wvq];
        int w = lane;
        float f0 = 0.f, f1x = 0.f, f1y = 0.f, f1z = 0.f;
#pragma unroll
        for (int u = 0; u < 32; ++u) {
            float w0 = W1_0e[u * 64 + w];
            float w1 = W1_1o[u * 64 + w];
            f0  += sx[u] * w0;
            f1x += sx[32 + u * 3 + 0] * w1;
            f1y += sx[32 + u * 3 + 1] * w1;
            f1z += sx[32 + u * 3 + 2] * w1;
        }
        f0 *= SC_W1; f1x *= SC_W1; f1y *= SC_W1; f1z *= SC_W1;
        if (w < 32) {
            featp[node * 128 + w]      = f0;
            featp[node * 128 + 32 + w] = f1x;
            featp[node * 128 + 64 + w] = f1y;
            featp[node * 128 + 96 + w] = f1z;
        } else {
            int ww = w - 32;
            out[node * 128 + ww] = COS_MIX * f0;
            out[node * 128 + 32 + ww * 3 + 0] = COS_MIX * f1x;
            out[node * 128 + 32 + ww * 3 + 1] = COS_MIX * f1y;
            out[node * 128 + 32 + ww * 3 + 2] = COS_MIX * f1z;
        }
        return;
    }

    // ---- mlp_scatter ----
    {
        const uint32x4* s = (const uint32x4*)wf;
        for (int i = threadIdx.x; i < 26 * 64; i += 256) wfl[i] = s[i];
    }
    __syncthreads();

    int wave_id = blockIdx.x * 4 + wvq;      // [0, 5000)
    int l31 = lane & 31;
    int lhi = lane >> 5;

    const f32x16 z16 = {0,0,0,0,0,0,0,0,0,0,0,0,0,0,0,0};
    unsigned short* shw = sh[wvq];
    uint32* obw = (uint32*)shw;              // fp8 staging overlay (4KB)
    unsigned short* obw16 = shw;

    for (int g = wave_id; g < N_EDGES / 32; g += MLP_BLOCKS * 4) {   // 2 iters
        int e0 = g * 32;

        halfx8 a0 = (halfx8)0;
        if (lane < 32) {
            int e = e0 + lane;
            const float* esp = edge_scalar + (size_t)e * 8;
            float4 p = *(const float4*)esp;
            float4 q = *(const float4*)(esp + 4);
            float4 av = *(const float4*)(edge_attr + (size_t)e * 4);
            int dn = dst_in[e];
            int sn = src_in[e];
            int pos = atomicAdd(&off[dn], 1);
            poss[wvq][lane] = pos;
            eaxs[wvq][lane] = av.x;
            uint4 rv;
            rv.x = __float_as_uint(av.y);
            rv.y = __float_as_uint(av.z);
            rv.z = __float_as_uint(av.w);
            rv.w = (uint32)sn;
            rec[pos] = rv;
            a0[0] = (_Float16)p.x; a0[1] = (_Float16)p.y;
            a0[2] = (_Float16)p.z; a0[3] = (_Float16)p.w;
            a0[4] = (_Float16)q.x; a0[5] = (_Float16)q.y;
            a0[6] = (_Float16)q.z; a0[7] = (_Float16)q.w;
        }

        // h1 GEMM: 2 MFMA (K=16, k>=8 zero-padded)
        f32x16 acc1[2];
#pragma unroll
        for (int nc = 0; nc < 2; ++nc) {
            halfx8 bb = __builtin_bit_cast(halfx8, wfl[nc * 64 + lane]);
            acc1[nc] = __builtin_amdgcn_mfma_f32_32x32x16_f16(a0, bb, z16, 0, 0, 0);
        }
#pragma unroll
        for (int nc = 0; nc < 2; ++nc)
#pragma unroll
            for (int reg = 0; reg < 16; ++reg) {
                float gv = gelu_fast(acc1[nc][reg] * SC_MLP1);
                int r = (reg & 3) + 8 * (reg >> 2) + 4 * lhi;
                int ix = r * 64 + 32 * nc + l31;
                shw[ix ^ ((r & 7) << 3)] = h16(gv);
            }
        halfx8 a1[4];
#pragma unroll
        for (int ks = 0; ks < 4; ++ks) {
            int ix = l31 * 64 + 16 * ks + lhi * 8;
            a1[ks] = __builtin_bit_cast(halfx8,
                       *(const uint32x4*)&shw[ix ^ ((lane & 7) << 3)]);
        }

        // h2 GEMM: 8 MFMA
        f32x16 acc2[2];
#pragma unroll
        for (int nc = 0; nc < 2; ++nc) {
            acc2[nc] = z16;
#pragma unroll
            for (int ks = 0; ks < 4; ++ks) {
                halfx8 bb = __builtin_bit_cast(halfx8, wfl[(2 + nc * 4 + ks) * 64 + lane]);
                acc2[nc] = __builtin_amdgcn_mfma_f32_32x32x16_f16(a1[ks], bb, acc2[nc], 0, 0, 0);
            }
        }
#pragma unroll
        for (int nc = 0; nc < 2; ++nc)
#pragma unroll
            for (int reg = 0; reg < 16; ++reg) {
                float gv = gelu_fast(acc2[nc][reg] * SC_MLP2);
                int r = (reg & 3) + 8 * (reg >> 2) + 4 * lhi;
                int ix = r * 64 + 32 * nc + l31;
                shw[ix ^ ((r & 7) << 3)] = h16(gv);
            }
        halfx8 a2[4];
#pragma unroll
        for (int ks = 0; ks < 4; ++ks) {
            int ix = l31 * 64 + 16 * ks + lhi * 8;
            a2[ks] = __builtin_bit_cast(halfx8,
                       *(const uint32x4*)&shw[ix ^ ((lane & 7) << 3)]);
        }

        // projection GEMM: 16 MFMA
        f32x16 accp[4];
#pragma unroll
        for (int m = 0; m < 4; ++m) {
            accp[m] = z16;
#pragma unroll
            for (int ks = 0; ks < 4; ++ks) {
                halfx8 bb = __builtin_bit_cast(halfx8, wfl[(10 + m * 4 + ks) * 64 + lane]);
                accp[m] = __builtin_amdgcn_mfma_f32_32x32x16_f16(a2[ks], bb, accp[m], 0, 0, 0);
            }
        }

        // fold ea.x, pack fp8 pairs into ob overlay (unswizzled rows)
#pragma unroll
        for (int reg = 0; reg < 16; ++reg) {
            int r = (reg & 3) + 8 * (reg >> 2) + 4 * lhi;
            float eax = eaxs[wvq][r];
            obw16[r * 64 + l31]      = pack_fp8_2(accp[0][reg] * eax, accp[1][reg]);
            obw16[r * 64 + 32 + l31] = pack_fp8_2(accp[2][reg] * eax, accp[3][reg]);
        }
        // store full rows: 128B contiguous per edge row (8 lanes x dwordx4)
#pragma unroll
        for (int pass = 0; pass < 4; ++pass) {
            int r = pass * 8 + (lane >> 3);
            int pos = poss[wvq][r];
            int c4 = (lane & 7) * 4;
            uint32x4 v = *(const uint32x4*)&obw[r * 32 + c4];
            *(uint32x4*)(wbuf + (size_t)pos * 32 + c4) = v;
        }
    }
}

// ================= K4: gather (8-deep pipelined consume) =====================
__global__ __launch_bounds__(256) void gather(const int* __restrict__ off,
                                              const int* __restrict__ cnt,
                                              const uint4* __restrict__ rec,
                                              const uint32* __restrict__ wbuf,
                                              const float* __restrict__ featp,
                                              const float* __restrict__ W2_0e,
                                              const float* __restrict__ W2_1o,
                                              float* __restrict__ out) {
    int wv = threadIdx.x >> 6;
    int lane = threadIdx.x & 63;
    int node = blockIdx.x * 4 + wv;
    int u = lane & 31;
    int half = lane >> 5;

    int end = __builtin_amdgcn_readfirstlane(off[node]);   // off mutated = end
    int beg = end - __builtin_amdgcn_readfirstlane(cnt[node]);

    float a0acc = 0.f, a1x = 0.f, a1y = 0.f, a1z = 0.f;
    int offA = u + half * 32, offB = 64 + u, offC = 96 + u;
    const ushrt* wbuf16 = (const ushrt*)wbuf;
    int uslot = (half << 5) + u;

    for (int i0 = beg; i0 < end; i0 += 64) {
        int nn = end - i0;
        if (nn > 64) nn = 64;
        int idx = i0 + ((lane < nn) ? lane : 0);
        uint4 rv = rec[idx];                       // coalesced batch of 64 records
        int eyv = (int)rv.x, ezv = (int)rv.y, ewv = (int)rv.z, svv = (int)rv.w;
        for (int j0 = 0; j0 < nn; j0 += 8) {
            uint32 wl_[8];
            float fa_[8], fb_[8], fc_[8], ey_[8], ez_[8], ew_[8];
#pragma unroll
            for (int t = 0; t < 8; ++t) {
                int j = j0 + t;
                int jc = (j < nn) ? j : nn - 1;
                ey_[t] = __uint_as_float((uint32)__builtin_amdgcn_readlane(eyv, jc));
                ez_[t] = __uint_as_float((uint32)__builtin_amdgcn_readlane(ezv, jc));
                ew_[t] = __uint_as_float((uint32)__builtin_amdgcn_readlane(ewv, jc));
                int s  = __builtin_amdgcn_readlane(svv, jc);
                uint32 wl = (uint32)wbuf16[(size_t)(i0 + jc) * 64 + uslot]; // linear 128B rows
                wl_[t] = (j < nn) ? wl : 0u;
                const float* fp = featp + (size_t)s * 128;
                fa_[t] = fp[offA];
                fb_[t] = fp[offB];
                fc_[t] = fp[offC];
            }
#pragma unroll
            for (int t = 0; t < 8; ++t) {
                f32x2 wab = __builtin_amdgcn_cvt_pk_f32_fp8((int)wl_[t], false);
                float wa = wab.x;
                float wb = wab.y;
                float va = half ? ey_[t] : 1.0f;
                float vb = half ? ez_[t] : 0.0f;
                float vc = half ? ew_[t] : 0.0f;
                float dot = fa_[t] * va + fb_[t] * vb + fc_[t] * vc;
                float w0s = half ? wb : wa;
                a0acc += w0s * dot;
                float m  = half ? wa : wb * fa_[t];
                float vx = half ? fa_[t] : ey_[t];
                float vy = half ? fb_[t] : ez_[t];
                float vz = half ? fc_[t] : ew_[t];
                a1x += m * vx; a1y += m * vy; a1z += m * vz;
            }
        }
    }

    __shared__ float red[4][256];
    float* r = red[wv];
    int c = (half << 5) + u;
    r[c] = a0acc;
    int b = 64 + c * 3;
    r[b] = a1x; r[b + 1] = a1y; r[b + 2] = a1z;
    __syncthreads();

    if (half == 0) {
        float acc = 0.f;
#pragma unroll 8
        for (int w = 0; w < 64; ++w) acc += r[w] * W2_0e[w * 32 + u];
        int o = node * 128 + u;
        out[o] = out[o] + SIN_CONV * acc;          // prefilled with COS_MIX*self
    } else {
        float c0 = 0.f, c1 = 0.f, c2 = 0.f;
#pragma unroll 8
        for (int w = 0; w < 64; ++w) {
            float bw = W2_1o[w * 32 + u];
            c0 += r[64 + w * 3 + 0] * bw;
            c1 += r[64 + w * 3 + 1] * bw;
            c2 += r[64 + w * 3 + 2] * bw;
        }
        int o = node * 128 + 32 + u * 3;
        out[o + 0] = out[o + 0] + SIN_CONV * c0;
        out[o + 1] = out[o + 1] + SIN_CONV * c1;
        out[o + 2] = out[o + 2] + SIN_CONV * c2;
    }
}

extern "C" void kernel_launch(void* const* d_in, const int* in_sizes, int n_in,
                              void* d_out, int out_size, void* d_ws, size_t ws_size,
                              hipStream_t stream) {
    const float* node_input  = (const float*)d_in[0];
    const float* edge_attr   = (const float*)d_in[1];
    const float* edge_scalar = (const float*)d_in[2];
    const float* W1_0e       = (const float*)d_in[3];
    const float* W1_1o       = (const float*)d_in[4];
    const float* W_mlp1      = (const float*)d_in[5];
    const float* W_mlp2      = (const float*)d_in[6];
    const float* Wp00        = (const float*)d_in[7];
    const float* Wp01        = (const float*)d_in[8];
    const float* Wp10        = (const float*)d_in[9];
    const float* Wp11        = (const float*)d_in[10];
    const float* W2_0e       = (const float*)d_in[11];
    const float* W2_1o       = (const float*)d_in[12];
    const int*   edge_src    = (const int*)d_in[13];
    const int*   edge_dst    = (const int*)d_in[14];
    float* ws   = (float*)d_ws;
    int*   wsI  = (int*)d_ws;
    uint32* wsU = (uint32*)d_ws;
    uint4* recp = (uint4*)(wsU + U_REC);
    float* outp = (float*)d_out;

    zero_cnt<<<40, 256, 0, stream>>>(wsI + I_CNT);
    k1_fused<<<K1_CNT_BLOCKS + K1_PREP_BLOCKS, 256, 0, stream>>>(
        edge_dst, wsI + I_CNT,
        W_mlp1, W_mlp2, Wp00, Wp01, Wp10, Wp11, wsU + U_WF);
    csr_scan<<<1, 1024, 0, stream>>>(wsI + I_CNT, wsI + I_OFF);
    k3_fused<<<MLP_BLOCKS + K3_NODE_BLOCKS, 256, 0, stream>>>(
        edge_scalar, edge_attr, edge_src, edge_dst, wsI + I_OFF,
        wsU + U_WF, wsU + U_WBUF, recp,
        node_input, W1_0e, W1_1o, ws + WS_FEATP, outp);
    gather<<<N_NODES / 4, 256, 0, stream>>>(wsI + I_OFF, wsI + I_CNT, recp,
                                            wsU + U_WBUF, ws + WS_FEATP,
                                            W2_0e, W2_1o, outp);
}

// Round 21
// 110.118 us; speedup vs baseline: 1.0379x; 1.0379x over previous
//
#include <hip/hip_runtime.h>

typedef unsigned int uint32;
typedef unsigned short ushrt;
typedef __attribute__((ext_vector_type(4))) float f32x4;
typedef __attribute__((ext_vector_type(16))) float f32x16;
typedef __attribute__((ext_vector_type(2))) float f32x2;
typedef __attribute__((ext_vector_type(8))) _Float16 halfx8;
typedef __attribute__((ext_vector_type(4))) uint32 uint32x4;

#define N_NODES 10000
#define N_EDGES 320000

// scales
#define SC_W1      0.17677669529663687f   // 1/sqrt(32)
#define SC_MLP1    0.35355339059327373f   // 1/sqrt(8)
#define SC_MLP2    0.125f                 // 1/sqrt(64)
#define INV_SQRT3  0.5773502691896258f
#define COS_MIX    0.9238795325112867f    // cos(pi/8)
#define SIN_CONV   0.04783542904563623f   // sin(pi/8) / sqrt(64)

// ws layout
#define WS_FEATP 0        // [N][128] floats, planar: f0 | f1x | f1y | f1z
#define I_CNT    1280000  // [N+1]
#define I_OFF    1290016  // [N+1]  (mutated by mlp branch; gather uses off-cnt)
#define U_REC    1300032  // [E] uint4: {ea.y, ea.z, ea.w bits, src}
#define U_WF     2580032  // 26 frags x 64 lanes x 4 uints (32x32 MFMA layout)
#define U_WBUF   2587200  // [E][32] uints = [E][64] fp8-pairs (128B rows), CSR order

__device__ __forceinline__ uint32 packh2(float a, float b) {
    _Float16 ha = (_Float16)a, hb = (_Float16)b;
    return (uint32)__builtin_bit_cast(unsigned short, ha) |
           ((uint32)__builtin_bit_cast(unsigned short, hb) << 16);
}
__device__ __forceinline__ unsigned short h16(float x) {
    _Float16 h = (_Float16)x;
    return __builtin_bit_cast(unsigned short, h);
}
__device__ __forceinline__ unsigned short pack_fp8_2(float a, float b) {
    return (unsigned short)(__builtin_amdgcn_cvt_pk_fp8_f32(a, b, 0, false) & 0xffff);
}
__device__ __forceinline__ float gelu_fast(float x) {
    float x2 = x * x;
    float z = x * __builtin_fmaf(0.03567740814f, x2, 0.7978845608f);
    float E = __builtin_amdgcn_exp2f(z * -2.885390082f);
    return x * __builtin_amdgcn_rcpf(1.0f + E);
}

// ================= K0: zero_cnt (replaces slow hipMemsetAsync fill) =========
__global__ __launch_bounds__(256) void zero_cnt(int* __restrict__ cnt) {
    int i = blockIdx.x * 256 + threadIdx.x;   // grid 40: 10240 >= 10001
    if (i <= N_NODES) cnt[i] = 0;
}

// ================= K1: csr_count | prep_frags (32x32 fragment layout) ========
#define K1_CNT_BLOCKS  1250
#define K1_PREP_BLOCKS 7
__global__ __launch_bounds__(256) void k1_fused(
        const int* __restrict__ edge_dst, int* __restrict__ cnt,
        const float* __restrict__ Wm1, const float* __restrict__ Wm2,
        const float* __restrict__ Wp00, const float* __restrict__ Wp01,
        const float* __restrict__ Wp10, const float* __restrict__ Wp11,
        uint32* __restrict__ wf) {
    int b = blockIdx.x;
    if (b < K1_CNT_BLOCKS) {
        int e = b * 256 + threadIdx.x;
        atomicAdd(&cnt[edge_dst[e]], 1);
    } else {
        int gid = (b - K1_CNT_BLOCKS) * 256 + threadIdx.x;
        if (gid >= 26 * 64) return;
        int f = gid >> 6, lane = gid & 63;
        int kb = (lane >> 5) * 8;
        int c31 = lane & 31;
        float vals[8];
        if (f < 2) {
            int c = 32 * f + c31;
#pragma unroll
            for (int j = 0; j < 8; ++j) { int k = kb + j; vals[j] = (k < 8) ? Wm1[k * 64 + c] : 0.f; }
        } else if (f < 10) {
            int idx = f - 2, nc = idx >> 2, ks = idx & 3;
            int c = 32 * nc + c31;
#pragma unroll
            for (int j = 0; j < 8; ++j) { int k = 16 * ks + kb + j; vals[j] = Wm2[k * 64 + c]; }
        } else {
            int idx = f - 10, m = idx >> 2, ks = idx & 3;
            const float* W = (m == 0) ? Wp00 : (m == 1) ? Wp01 : (m == 2) ? Wp10 : Wp11;
            float sc = (m == 3) ? 0.125f * INV_SQRT3 : 0.125f;
#pragma unroll
            for (int j = 0; j < 8; ++j) { int k = 16 * ks + kb + j; vals[j] = W[k * 32 + c31] * sc; }
        }
        uint32* o = wf + f * 256 + lane * 4;
#pragma unroll
        for (int w = 0; w < 4; ++w) o[w] = packh2(vals[2 * w], vals[2 * w + 1]);
    }
}

// ================= K2: csr_scan (single block, 1024 threads) =================
__global__ __launch_bounds__(1024) void csr_scan(const int* __restrict__ cnt,
                                                 int* __restrict__ off) {
    __shared__ int partial[1024];
    int t = threadIdx.x;
    const int CHUNK = 10;
    int base = t * CHUNK;
    int s = 0;
#pragma unroll
    for (int j = 0; j < CHUNK; ++j) {
        int idx = base + j;
        s += (idx < N_NODES) ? cnt[idx] : 0;
    }
    partial[t] = s;
    __syncthreads();
    for (int o = 1; o < 1024; o <<= 1) {
        int v = partial[t];
        int add = (t >= o) ? partial[t - o] : 0;
        __syncthreads();
        partial[t] = v + add;
        __syncthreads();
    }
    int run = (t > 0) ? partial[t - 1] : 0;
    for (int j = 0; j < CHUNK; ++j) {
        int idx = base + j;
        if (idx < N_NODES) {
            off[idx] = run;
            run += cnt[idx];
        }
    }
    if (t == 1023) off[N_NODES] = run;
}

// ================= K3: mlp_scatter (32-edge groups, 32x32 MFMA) + node ======
#define MLP_BLOCKS 1250
#define K3_NODE_BLOCKS 2500
__global__ __launch_bounds__(256, 3) void k3_fused(
        const float* __restrict__ edge_scalar, const float* __restrict__ edge_attr,
        const int* __restrict__ src_in, const int* __restrict__ dst_in,
        int* __restrict__ off,
        const uint32* __restrict__ wf,
        uint32* __restrict__ wbuf, uint4* __restrict__ rec,
        const float* __restrict__ x,
        const float* __restrict__ W1_0e, const float* __restrict__ W1_1o,
        float* __restrict__ featp, float* __restrict__ out) {
    __shared__ uint32x4 wfl[26 * 64];        // 26KB: all weight fragments
    __shared__ unsigned short sh[4][2048];   // 16KB: per-wave 32x64 f16 tile / fp8 ob
    __shared__ float eaxs[4][32];
    __shared__ int   poss[4][32];
    __shared__ float xrow[4][128];           // node branch

    int lane = threadIdx.x & 63;
    int wvq = threadIdx.x >> 6;

    if (blockIdx.x >= MLP_BLOCKS) {
        // ---- node_transform ----
        int node = (blockIdx.x - MLP_BLOCKS) * 4 + wvq;
        float2 v = *(const float2*)(x + (size_t)node * 128 + lane * 2);
        xrow[wvq][lane * 2]     = v.x;
        xrow[wvq][lane * 2 + 1] = v.y;
        __syncthreads();
        const float* sx = xrow[wvq];
        int w = lane;
        float f0 = 0.f, f1x = 0.f, f1y = 0.f, f1z = 0.f;
#pragma unroll
        for (int u = 0; u < 32; ++u) {
            float w0 = W1_0e[u * 64 + w];
            float w1 = W1_1o[u * 64 + w];
            f0  += sx[u] * w0;
            f1x += sx[32 + u * 3 + 0] * w1;
            f1y += sx[32 + u * 3 + 1] * w1;
            f1z += sx[32 + u * 3 + 2] * w1;
        }
        f0 *= SC_W1; f1x *= SC_W1; f1y *= SC_W1; f1z *= SC_W1;
        if (w < 32) {
            featp[node * 128 + w]      = f0;
            featp[node * 128 + 32 + w] = f1x;
            featp[node * 128 + 64 + w] = f1y;
            featp[node * 128 + 96 + w] = f1z;
        } else {
            int ww = w - 32;
            out[node * 128 + ww] = COS_MIX * f0;
            out[node * 128 + 32 + ww * 3 + 0] = COS_MIX * f1x;
            out[node * 128 + 32 + ww * 3 + 1] = COS_MIX * f1y;
            out[node * 128 + 32 + ww * 3 + 2] = COS_MIX * f1z;
        }
        return;
    }

    // ---- mlp_scatter ----
    {
        const uint32x4* s = (const uint32x4*)wf;
        for (int i = threadIdx.x; i < 26 * 64; i += 256) wfl[i] = s[i];
    }
    __syncthreads();

    int wave_id = blockIdx.x * 4 + wvq;      // [0, 5000)
    int l31 = lane & 31;
    int lhi = lane >> 5;

    const f32x16 z16 = {0,0,0,0,0,0,0,0,0,0,0,0,0,0,0,0};
    unsigned short* shw = sh[wvq];
    uint32* obw = (uint32*)shw;              // fp8 staging overlay (4KB)
    unsigned short* obw16 = shw;

    for (int g = wave_id; g < N_EDGES / 32; g += MLP_BLOCKS * 4) {   // 2 iters
        int e0 = g * 32;

        halfx8 a0 = (halfx8)0;
        if (lane < 32) {
            int e = e0 + lane;
            const float* esp = edge_scalar + (size_t)e * 8;
            float4 p = *(const float4*)esp;
            float4 q = *(const float4*)(esp + 4);
            float4 av = *(const float4*)(edge_attr + (size_t)e * 4);
            int dn = dst_in[e];
            int sn = src_in[e];
            int pos = atomicAdd(&off[dn], 1);
            poss[wvq][lane] = pos;
            eaxs[wvq][lane] = av.x;
            uint4 rv;
            rv.x = __float_as_uint(av.y);
            rv.y = __float_as_uint(av.z);
            rv.z = __float_as_uint(av.w);
            rv.w = (uint32)sn;
            rec[pos] = rv;
            a0[0] = (_Float16)p.x; a0[1] = (_Float16)p.y;
            a0[2] = (_Float16)p.z; a0[3] = (_Float16)p.w;
            a0[4] = (_Float16)q.x; a0[5] = (_Float16)q.y;
            a0[6] = (_Float16)q.z; a0[7] = (_Float16)q.w;
        }

        // h1 GEMM: 2 MFMA (K=16, k>=8 zero-padded)
        f32x16 acc1[2];
#pragma unroll
        for (int nc = 0; nc < 2; ++nc) {
            halfx8 bb = __builtin_bit_cast(halfx8, wfl[nc * 64 + lane]);
            acc1[nc] = __builtin_amdgcn_mfma_f32_32x32x16_f16(a0, bb, z16, 0, 0, 0);
        }
#pragma unroll
        for (int nc = 0; nc < 2; ++nc)
#pragma unroll
            for (int reg = 0; reg < 16; ++reg) {
                float gv = gelu_fast(acc1[nc][reg] * SC_MLP1);
                int r = (reg & 3) + 8 * (reg >> 2) + 4 * lhi;
                int ix = r * 64 + 32 * nc + l31;
                shw[ix ^ ((r & 7) << 3)] = h16(gv);
            }
        halfx8 a1[4];
#pragma unroll
        for (int ks = 0; ks < 4; ++ks) {
            int ix = l31 * 64 + 16 * ks + lhi * 8;
            a1[ks] = __builtin_bit_cast(halfx8,
                       *(const uint32x4*)&shw[ix ^ ((lane & 7) << 3)]);
        }

        // h2 GEMM: 8 MFMA
        f32x16 acc2[2];
#pragma unroll
        for (int nc = 0; nc < 2; ++nc) {
            acc2[nc] = z16;
#pragma unroll
            for (int ks = 0; ks < 4; ++ks) {
                halfx8 bb = __builtin_bit_cast(halfx8, wfl[(2 + nc * 4 + ks) * 64 + lane]);
                acc2[nc] = __builtin_amdgcn_mfma_f32_32x32x16_f16(a1[ks], bb, acc2[nc], 0, 0, 0);
            }
        }
#pragma unroll
        for (int nc = 0; nc < 2; ++nc)
#pragma unroll
            for (int reg = 0; reg < 16; ++reg) {
                float gv = gelu_fast(acc2[nc][reg] * SC_MLP2);
                int r = (reg & 3) + 8 * (reg >> 2) + 4 * lhi;
                int ix = r * 64 + 32 * nc + l31;
                shw[ix ^ ((r & 7) << 3)] = h16(gv);
            }
        halfx8 a2[4];
#pragma unroll
        for (int ks = 0; ks < 4; ++ks) {
            int ix = l31 * 64 + 16 * ks + lhi * 8;
            a2[ks] = __builtin_bit_cast(halfx8,
                       *(const uint32x4*)&shw[ix ^ ((lane & 7) << 3)]);
        }

        // projection GEMM: 16 MFMA
        f32x16 accp[4];
#pragma unroll
        for (int m = 0; m < 4; ++m) {
            accp[m] = z16;
#pragma unroll
            for (int ks = 0; ks < 4; ++ks) {
                halfx8 bb = __builtin_bit_cast(halfx8, wfl[(10 + m * 4 + ks) * 64 + lane]);
                accp[m] = __builtin_amdgcn_mfma_f32_32x32x16_f16(a2[ks], bb, accp[m], 0, 0, 0);
            }
        }

        // fold ea.x, pack fp8 pairs into ob overlay (unswizzled rows)
#pragma unroll
        for (int reg = 0; reg < 16; ++reg) {
            int r = (reg & 3) + 8 * (reg >> 2) + 4 * lhi;
            float eax = eaxs[wvq][r];
            obw16[r * 64 + l31]      = pack_fp8_2(accp[0][reg] * eax, accp[1][reg]);
            obw16[r * 64 + 32 + l31] = pack_fp8_2(accp[2][reg] * eax, accp[3][reg]);
        }
        // store full rows: 128B contiguous per edge row (8 lanes x dwordx4)
#pragma unroll
        for (int pass = 0; pass < 4; ++pass) {
            int r = pass * 8 + (lane >> 3);
            int pos = poss[wvq][r];
            int c4 = (lane & 7) * 4;
            uint32x4 v = *(const uint32x4*)&obw[r * 32 + c4];
            *(uint32x4*)(wbuf + (size_t)pos * 32 + c4) = v;
        }
    }
}

// ================= K4: gather (all-linear streams + featp table) =============
__global__ __launch_bounds__(256) void gather(const int* __restrict__ off,
                                              const int* __restrict__ cnt,
                                              const uint4* __restrict__ rec,
                                              const uint32* __restrict__ wbuf,
                                              const float* __restrict__ featp,
                                              const float* __restrict__ W2_0e,
                                              const float* __restrict__ W2_1o,
                                              float* __restrict__ out) {
    int wv = threadIdx.x >> 6;
    int lane = threadIdx.x & 63;
    int node = blockIdx.x * 4 + wv;
    int u = lane & 31;
    int half = lane >> 5;

    int end = __builtin_amdgcn_readfirstlane(off[node]);   // off mutated = end
    int beg = end - __builtin_amdgcn_readfirstlane(cnt[node]);

    float a0acc = 0.f, a1x = 0.f, a1y = 0.f, a1z = 0.f;
    int offA = u + half * 32, offB = 64 + u, offC = 96 + u;
    const ushrt* wbuf16 = (const ushrt*)wbuf;
    int uslot = (half << 5) + u;

    for (int i0 = beg; i0 < end; i0 += 64) {
        int nn = end - i0;
        if (nn > 64) nn = 64;
        int idx = i0 + ((lane < nn) ? lane : 0);
        uint4 rv = rec[idx];                       // coalesced batch of 64 records
        int eyv = (int)rv.x, ezv = (int)rv.y, ewv = (int)rv.z, svv = (int)rv.w;
        for (int j0 = 0; j0 < nn; j0 += 4) {
            uint32 wl_[4];
            float fa_[4], fb_[4], fc_[4], ey_[4], ez_[4], ew_[4];
#pragma unroll
            for (int t = 0; t < 4; ++t) {
                int j = j0 + t;
                int jc = (j < nn) ? j : nn - 1;
                ey_[t] = __uint_as_float((uint32)__builtin_amdgcn_readlane(eyv, jc));
                ez_[t] = __uint_as_float((uint32)__builtin_amdgcn_readlane(ezv, jc));
                ew_[t] = __uint_as_float((uint32)__builtin_amdgcn_readlane(ewv, jc));
                int s  = __builtin_amdgcn_readlane(svv, jc);
                uint32 wl = (uint32)wbuf16[(size_t)(i0 + jc) * 64 + uslot]; // linear 128B rows
                wl_[t] = (j < nn) ? wl : 0u;
                const float* fp = featp + (size_t)s * 128;
                fa_[t] = fp[offA];
                fb_[t] = fp[offB];
                fc_[t] = fp[offC];
            }
#pragma unroll
            for (int t = 0; t < 4; ++t) {
                f32x2 wab = __builtin_amdgcn_cvt_pk_f32_fp8((int)wl_[t], false);
                float wa = wab.x;
                float wb = wab.y;
                float va = half ? ey_[t] : 1.0f;
                float vb = half ? ez_[t] : 0.0f;
                float vc = half ? ew_[t] : 0.0f;
                float dot = fa_[t] * va + fb_[t] * vb + fc_[t] * vc;
                float w0s = half ? wb : wa;
                a0acc += w0s * dot;
                float m  = half ? wa : wb * fa_[t];
                float vx = half ? fa_[t] : ey_[t];
                float vy = half ? fb_[t] : ez_[t];
                float vz = half ? fc_[t] : ew_[t];
                a1x += m * vx; a1y += m * vy; a1z += m * vz;
            }
        }
    }

    __shared__ float red[4][256];
    float* r = red[wv];
    int c = (half << 5) + u;
    r[c] = a0acc;
    int b = 64 + c * 3;
    r[b] = a1x; r[b + 1] = a1y; r[b + 2] = a1z;
    __syncthreads();

    if (half == 0) {
        float acc = 0.f;
#pragma unroll 8
        for (int w = 0; w < 64; ++w) acc += r[w] * W2_0e[w * 32 + u];
        int o = node * 128 + u;
        out[o] = out[o] + SIN_CONV * acc;          // prefilled with COS_MIX*self
    } else {
        float c0 = 0.f, c1 = 0.f, c2 = 0.f;
#pragma unroll 8
        for (int w = 0; w < 64; ++w) {
            float bw = W2_1o[w * 32 + u];
            c0 += r[64 + w * 3 + 0] * bw;
            c1 += r[64 + w * 3 + 1] * bw;
            c2 += r[64 + w * 3 + 2] * bw;
        }
        int o = node * 128 + 32 + u * 3;
        out[o + 0] = out[o + 0] + SIN_CONV * c0;
        out[o + 1] = out[o + 1] + SIN_CONV * c1;
        out[o + 2] = out[o + 2] + SIN_CONV * c2;
    }
}

extern "C" void kernel_launch(void* const* d_in, const int* in_sizes, int n_in,
                              void* d_out, int out_size, void* d_ws, size_t ws_size,
                              hipStream_t stream) {
    const float* node_input  = (const float*)d_in[0];
    const float* edge_attr   = (const float*)d_in[1];
    const float* edge_scalar = (const float*)d_in[2];
    const float* W1_0e       = (const float*)d_in[3];
    const float* W1_1o       = (const float*)d_in[4];
    const float* W_mlp1      = (const float*)d_in[5];
    const float* W_mlp2      = (const float*)d_in[6];
    const float* Wp00        = (const float*)d_in[7];
    const float* Wp01        = (const float*)d_in[8];
    const float* Wp10        = (const float*)d_in[9];
    const float* Wp11        = (const float*)d_in[10];
    const float* W2_0e       = (const float*)d_in[11];
    const float* W2_1o       = (const float*)d_in[12];
    const int*   edge_src    = (const int*)d_in[13];
    const int*   edge_dst    = (const int*)d_in[14];
    float* ws   = (float*)d_ws;
    int*   wsI  = (int*)d_ws;
    uint32* wsU = (uint32*)d_ws;
    uint4* recp = (uint4*)(wsU + U_REC);
    float* outp = (float*)d_out;

    zero_cnt<<<40, 256, 0, stream>>>(wsI + I_CNT);
    k1_fused<<<K1_CNT_BLOCKS + K1_PREP_BLOCKS, 256, 0, stream>>>(
        edge_dst, wsI + I_CNT,
        W_mlp1, W_mlp2, Wp00, Wp01, Wp10, Wp11, wsU + U_WF);
    csr_scan<<<1, 1024, 0, stream>>>(wsI + I_CNT, wsI + I_OFF);
    k3_fused<<<MLP_BLOCKS + K3_NODE_BLOCKS, 256, 0, stream>>>(
        edge_scalar, edge_attr, edge_src, edge_dst, wsI + I_OFF,
        wsU + U_WF, wsU + U_WBUF, recp,
        node_input, W1_0e, W1_1o, ws + WS_FEATP, outp);
    gather<<<N_NODES / 4, 256, 0, stream>>>(wsI + I_OFF, wsI + I_CNT, recp,
                                            wsU + U_WBUF, ws + WS_FEATP,
                                            W2_0e, W2_1o, outp);
}